// Round 1
// baseline (919.419 us; speedup 1.0000x reference)
//
#include <hip/hip_runtime.h>
#include <cstdint>
#include <cstddef>

#define D_    768
#define ROWS  32768      // B*N = 32*1024
#define MTOT  65536      // 2*ROWS (x1 rows then x2 rows)
#define QKV_N 2304       // q|k|v concatenated output columns
#define HID   192
#define KMLP  1536

typedef __attribute__((ext_vector_type(4))) float f32x4;
typedef __attribute__((ext_vector_type(8))) short s16x8;

__device__ inline unsigned short f2bf(float f) {
  union { float f; uint32_t u; } c; c.f = f;
  uint32_t r = c.u + 0x7FFFu + ((c.u >> 16) & 1u);
  return (unsigned short)(r >> 16);
}
__device__ inline float bf2f(unsigned short h) {
  union { uint32_t u; float f; } c; c.u = ((uint32_t)h) << 16;
  return c.f;
}

__device__ inline void gld_lds16(const void* g, void* l) {
  __builtin_amdgcn_global_load_lds(
      (const __attribute__((address_space(1))) void*)g,
      (__attribute__((address_space(3))) void*)l, 16, 0, 0);
}

// ---- convert x1,x2 (fp32) -> xb (bf16), stacked [x1; x2] = [65536, 768]
__global__ void k_convert_x(const float* __restrict__ x1, const float* __restrict__ x2,
                            unsigned short* __restrict__ xb) {
  size_t i = ((size_t)blockIdx.x * blockDim.x + threadIdx.x) * 4;
  const size_t n1 = (size_t)ROWS * D_;
  if (i >= 2 * n1) return;
  const float* src = (i < n1) ? (x1 + i) : (x2 + (i - n1));
  float4 v = *(const float4*)src;
  union { unsigned short u[4]; uint2 p; } o;
  o.u[0] = f2bf(v.x); o.u[1] = f2bf(v.y); o.u[2] = f2bf(v.z); o.u[3] = f2bf(v.w);
  *(uint2*)(xb + i) = o.p;
}

// ---- convert weights: Wt[n][k] = W[k][n] (bf16, transposed), Wq|Wk|Wv stacked rows;
// ---- W1t[n][k] = W1[k][n] (192 x 1536)
__global__ void k_convert_w(const float* __restrict__ Wq, const float* __restrict__ Wk,
                            const float* __restrict__ Wv, const float* __restrict__ W1,
                            unsigned short* __restrict__ Wt, unsigned short* __restrict__ W1t) {
  int idx = blockIdx.x * 256 + threadIdx.x;
  if (idx < QKV_N * D_) {
    int n = idx / D_, k = idx - n * D_;
    const float* W = (n < D_) ? Wq : ((n < 2 * D_) ? Wk : Wv);
    int nn = n % D_;
    Wt[idx] = f2bf(W[k * D_ + nn]);
    return;
  }
  idx -= QKV_N * D_;
  if (idx < HID * KMLP) {
    int n = idx / KMLP, k = idx - n * KMLP;
    W1t[idx] = f2bf(W1[k * HID + n]);
  }
}

// ---- nk[j] = sum_k noise[k] * Wk[k][j]  (bf16 out)
__global__ void k_noise_wk(const float* __restrict__ noise, const float* __restrict__ Wk,
                           unsigned short* __restrict__ nk) {
  int j = blockIdx.x * 256 + threadIdx.x;
  if (j >= D_) return;
  float s = 0.f;
  for (int k = 0; k < D_; ++k) s += noise[k] * Wk[k * D_ + j];
  nk[j] = f2bf(s);
}

// ---- qkv GEMM: C[65536,2304] = A[65536,768] @ Bt[2304,768]^T  (bf16 in, bf16 out)
// m97 structure: 128x128 tile, BK=32, 4 waves (2x2), 16x16x32 MFMA, global_load_lds x16
__launch_bounds__(256)
__global__ void k_gemm_qkv(const unsigned short* __restrict__ A,
                           const unsigned short* __restrict__ Bt,
                           unsigned short* __restrict__ C) {
  __shared__ __align__(16) short As[128 * 32];
  __shared__ __align__(16) short Bs[128 * 32];
  const int tid = threadIdx.x;
  const int m0 = blockIdx.y * 128;
  const int n0 = blockIdx.x * 128;
  const int lane = tid & 63, wave = tid >> 6;
  const int wm = (wave >> 1) * 64, wn = (wave & 1) * 64;
  const int quad = lane >> 4, mr = lane & 15;
  f32x4 acc[4][4];
#pragma unroll
  for (int i = 0; i < 4; ++i)
#pragma unroll
    for (int j = 0; j < 4; ++j) acc[i][j] = (f32x4){0.f, 0.f, 0.f, 0.f};

  const int ra = tid >> 2;          // 0..63
  const int kc = (tid & 3) * 8;
  for (int k0 = 0; k0 < D_; k0 += 32) {
    __syncthreads();
    gld_lds16(A + (size_t)(m0 + ra) * D_ + k0 + kc,       &As[tid * 8]);
    gld_lds16(A + (size_t)(m0 + 64 + ra) * D_ + k0 + kc,  &As[2048 + tid * 8]);
    gld_lds16(Bt + (size_t)(n0 + ra) * D_ + k0 + kc,      &Bs[tid * 8]);
    gld_lds16(Bt + (size_t)(n0 + 64 + ra) * D_ + k0 + kc, &Bs[2048 + tid * 8]);
    __syncthreads();
    s16x8 a[4], b[4];
#pragma unroll
    for (int i = 0; i < 4; ++i)
      a[i] = *(const s16x8*)&As[(wm + i * 16 + mr) * 32 + quad * 8];
#pragma unroll
    for (int j = 0; j < 4; ++j)
      b[j] = *(const s16x8*)&Bs[(wn + j * 16 + mr) * 32 + quad * 8];
#pragma unroll
    for (int i = 0; i < 4; ++i)
#pragma unroll
      for (int j = 0; j < 4; ++j)
        acc[i][j] = __builtin_amdgcn_mfma_f32_16x16x32_bf16(a[i], b[j], acc[i][j], 0, 0, 0);
  }
#pragma unroll
  for (int i = 0; i < 4; ++i) {
    int row = m0 + wm + i * 16 + quad * 4;  // C/D: row=(lane>>4)*4+reg, col=lane&15
#pragma unroll
    for (int j = 0; j < 4; ++j) {
      int col = n0 + wn + j * 16 + mr;
#pragma unroll
      for (int t = 0; t < 4; ++t)
        C[(size_t)(row + t) * QKV_N + col] = f2bf(acc[i][j][t]);
    }
  }
}

// ---- MLP GEMM: h = gelu([xs,xo]@W1 + b1); partial rel logit = h @ W2 (atomicAdd)
// tile 128x64, BK=32, 4 waves stacked in M (32 rows each), acc 2x4
__launch_bounds__(256)
__global__ void k_gemm_mlp(const unsigned short* __restrict__ xb,
                           const unsigned short* __restrict__ W1t,
                           const float* __restrict__ b1,
                           const float* __restrict__ W2,
                           float* __restrict__ rel) {
  __shared__ __align__(16) short As[128 * 32];
  __shared__ __align__(16) short Bs[64 * 32];
  const int tid = threadIdx.x;
  const int dir = blockIdx.z;
  const int m0 = blockIdx.y * 128;
  const int n0 = blockIdx.x * 64;
  const int lane = tid & 63, wave = tid >> 6;
  const int wm = wave * 32;
  const int quad = lane >> 4, mr = lane & 15;
  f32x4 acc[2][4];
#pragma unroll
  for (int i = 0; i < 2; ++i)
#pragma unroll
    for (int j = 0; j < 4; ++j) acc[i][j] = (f32x4){0.f, 0.f, 0.f, 0.f};

  const unsigned short* xfirst  = xb + (dir ? (size_t)ROWS * D_ : 0);
  const unsigned short* xsecond = xb + (dir ? 0 : (size_t)ROWS * D_);
  const int ra = tid >> 2, kc = (tid & 3) * 8;
  for (int k0 = 0; k0 < KMLP; k0 += 32) {
    const unsigned short* src = (k0 < D_) ? xfirst : xsecond;
    const int kk = (k0 < D_) ? k0 : k0 - D_;
    __syncthreads();
    gld_lds16(src + (size_t)(m0 + ra) * D_ + kk + kc,      &As[tid * 8]);
    gld_lds16(src + (size_t)(m0 + 64 + ra) * D_ + kk + kc, &As[2048 + tid * 8]);
    gld_lds16(W1t + (size_t)(n0 + ra) * KMLP + k0 + kc,    &Bs[tid * 8]);
    __syncthreads();
    s16x8 a[2], b[4];
#pragma unroll
    for (int i = 0; i < 2; ++i)
      a[i] = *(const s16x8*)&As[(wm + i * 16 + mr) * 32 + quad * 8];
#pragma unroll
    for (int j = 0; j < 4; ++j)
      b[j] = *(const s16x8*)&Bs[(j * 16 + mr) * 32 + quad * 8];
#pragma unroll
    for (int i = 0; i < 2; ++i)
#pragma unroll
      for (int j = 0; j < 4; ++j)
        acc[i][j] = __builtin_amdgcn_mfma_f32_16x16x32_bf16(a[i], b[j], acc[i][j], 0, 0, 0);
  }
  float part[2][4] = {{0.f, 0.f, 0.f, 0.f}, {0.f, 0.f, 0.f, 0.f}};
#pragma unroll
  for (int j = 0; j < 4; ++j) {
    int col = n0 + j * 16 + mr;
    float b1v = b1[col];
    float w2v = W2[col];
#pragma unroll
    for (int i = 0; i < 2; ++i)
#pragma unroll
      for (int t = 0; t < 4; ++t) {
        float h = acc[i][j][t] + b1v;
        h = 0.5f * h * (1.f + erff(h * 0.70710678118654752f));  // exact gelu
        part[i][t] += h * w2v;
      }
  }
#pragma unroll
  for (int m = 1; m < 16; m <<= 1)
#pragma unroll
    for (int i = 0; i < 2; ++i)
#pragma unroll
      for (int t = 0; t < 4; ++t)
        part[i][t] += __shfl_xor(part[i][t], m, 64);
  if (mr == 0) {
#pragma unroll
    for (int i = 0; i < 2; ++i) {
      int row = m0 + wm + i * 16 + quad * 4;
#pragma unroll
      for (int t = 0; t < 4; ++t)
        atomicAdd(&rel[(size_t)dir * ROWS + row + t], part[i][t]);
    }
  }
}

// ---- fusion: one wave per row-pair; 6 dots, softmax over {self, gated-cross}, output
__launch_bounds__(256)
__global__ void k_fuse(const float* __restrict__ x1, const float* __restrict__ x2,
                       const unsigned short* __restrict__ qkv,
                       const unsigned short* __restrict__ nk,
                       const float* __restrict__ rel, const float* __restrict__ b2,
                       float* __restrict__ y) {
  const int row = blockIdx.x * 4 + (threadIdx.x >> 6);
  const int lane = threadIdx.x & 63;
  const unsigned short* L1 = qkv + (size_t)row * QKV_N;
  const unsigned short* L2 = qkv + (size_t)(row + ROWS) * QKV_N;
  float d11 = 0.f, d12 = 0.f, d21 = 0.f, d22 = 0.f, qn1 = 0.f, qn2 = 0.f;
  for (int c = lane; c < 96; c += 64) {
    const int off = c * 8;
    s16x8 q1 = *(const s16x8*)(L1 + off);
    s16x8 k1 = *(const s16x8*)(L1 + D_ + off);
    s16x8 q2 = *(const s16x8*)(L2 + off);
    s16x8 k2 = *(const s16x8*)(L2 + D_ + off);
    s16x8 nv = *(const s16x8*)(nk + off);
#pragma unroll
    for (int e = 0; e < 8; ++e) {
      float fq1 = bf2f(q1[e]), fk1 = bf2f(k1[e]);
      float fq2 = bf2f(q2[e]), fk2 = bf2f(k2[e]);
      float fn = bf2f(nv[e]);
      d11 += fq1 * fk1; d12 += fq1 * fk2;
      d21 += fq2 * fk1; d22 += fq2 * fk2;
      qn1 += fq1 * fn;  qn2 += fq2 * fn;
    }
  }
#pragma unroll
  for (int m = 1; m < 64; m <<= 1) {
    d11 += __shfl_xor(d11, m, 64);
    d12 += __shfl_xor(d12, m, 64);
    d21 += __shfl_xor(d21, m, 64);
    d22 += __shfl_xor(d22, m, 64);
    qn1 += __shfl_xor(qn1, m, 64);
    qn2 += __shfl_xor(qn2, m, 64);
  }
  const float scale = 0.0360843918243516f;  // 768^-0.5
  const float b2v = b2[0];
  const float r1 = 1.f / (1.f + expf(-(rel[row] + b2v)));
  const float r2 = 1.f / (1.f + expf(-(rel[ROWS + row] + b2v)));
  const float ds1 = (d11 + qn1) * scale, dc1 = r1 * d12 * scale;
  const float ds2 = (d22 + qn2) * scale, dc2 = r2 * d21 * scale;
  const float ws1 = 1.f / (1.f + expf(dc1 - ds1)), wc1 = 1.f - ws1;
  const float ws2 = 1.f / (1.f + expf(dc2 - ds2)), wc2 = 1.f - ws2;
  const float* X1 = x1 + (size_t)row * D_;
  const float* X2 = x2 + (size_t)row * D_;
  float* Y1 = y + (size_t)row * D_;
  float* Y2 = y + (size_t)(ROWS + row) * D_;
  for (int c = lane; c < 96; c += 64) {
    const int off = c * 8;
    s16x8 v1 = *(const s16x8*)(L1 + 2 * D_ + off);
    s16x8 v2 = *(const s16x8*)(L2 + 2 * D_ + off);
    union F8 { float4 v[2]; float f[8]; };
    F8 a1, a2, o1, o2;
    a1.v[0] = *(const float4*)(X1 + off); a1.v[1] = *(const float4*)(X1 + off + 4);
    a2.v[0] = *(const float4*)(X2 + off); a2.v[1] = *(const float4*)(X2 + off + 4);
#pragma unroll
    for (int e = 0; e < 8; ++e) {
      float fv1 = bf2f(v1[e]), fv2 = bf2f(v2[e]);
      o1.f[e] = a1.f[e] + ws1 * fv1 + wc1 * fv2;
      o2.f[e] = a2.f[e] + ws2 * fv2 + wc2 * fv1;
    }
    *(float4*)(Y1 + off) = o1.v[0]; *(float4*)(Y1 + off + 4) = o1.v[1];
    *(float4*)(Y2 + off) = o2.v[0]; *(float4*)(Y2 + off + 4) = o2.v[1];
  }
}

extern "C" void kernel_launch(void* const* d_in, const int* in_sizes, int n_in,
                              void* d_out, int out_size, void* d_ws, size_t ws_size,
                              hipStream_t stream) {
  const float* x1 = (const float*)d_in[0];
  const float* x2 = (const float*)d_in[1];
  const float* Wq = (const float*)d_in[2];
  const float* Wk = (const float*)d_in[3];
  const float* Wv = (const float*)d_in[4];
  const float* noise = (const float*)d_in[5];
  const float* W1 = (const float*)d_in[6];
  const float* b1 = (const float*)d_in[7];
  const float* W2 = (const float*)d_in[8];
  const float* b2 = (const float*)d_in[9];
  float* y = (float*)d_out;

  char* ws = (char*)d_ws;
  size_t off = 0;
  auto alloc = [&](size_t bytes) {
    char* p = ws + off;
    off += (bytes + 255) & ~(size_t)255;
    return p;
  };
  unsigned short* xb  = (unsigned short*)alloc((size_t)MTOT * D_ * 2);      // 100.7 MB
  unsigned short* qkv = (unsigned short*)alloc((size_t)MTOT * QKV_N * 2);   // 302 MB
  unsigned short* Wt  = (unsigned short*)alloc((size_t)QKV_N * D_ * 2);
  unsigned short* W1t = (unsigned short*)alloc((size_t)HID * KMLP * 2);
  unsigned short* nk  = (unsigned short*)alloc((size_t)D_ * 2);
  float* rel          = (float*)alloc((size_t)2 * ROWS * 4);

  hipMemsetAsync(rel, 0, (size_t)2 * ROWS * 4, stream);

  {
    size_t nthreads = (size_t)MTOT * D_ / 4;
    k_convert_x<<<dim3((nthreads + 255) / 256), 256, 0, stream>>>(x1, x2, xb);
  }
  {
    int total = QKV_N * D_ + HID * KMLP;
    k_convert_w<<<dim3((total + 255) / 256), 256, 0, stream>>>(Wq, Wk, Wv, W1, Wt, W1t);
  }
  k_noise_wk<<<dim3(3), 256, 0, stream>>>(noise, Wk, nk);

  dim3 g1(QKV_N / 128, MTOT / 128);  // (18, 512)
  k_gemm_qkv<<<g1, 256, 0, stream>>>(xb, Wt, qkv);

  dim3 g2(HID / 64, ROWS / 128, 2);  // (3, 256, 2)
  k_gemm_mlp<<<g2, 256, 0, stream>>>(xb, W1t, b1, W2, rel);

  k_fuse<<<dim3(ROWS / 4), 256, 0, stream>>>(x1, x2, qkv, nk, rel, b2, y);
}

// Round 2
// 894.280 us; speedup vs baseline: 1.0281x; 1.0281x over previous
//
#include <hip/hip_runtime.h>
#include <cstdint>
#include <cstddef>

#define D_    768
#define ROWS  32768      // row pairs (B*N)
#define MTOT  65536      // interleaved rows: 2i = x1_i, 2i+1 = x2_i
#define NMAIN 1536       // [ v (768) | c (768) ]
#define HID   192
#define KMLP  1536
#define NMLP  384

typedef __attribute__((ext_vector_type(4))) float f32x4;
typedef __attribute__((ext_vector_type(8))) short s16x8;

__device__ inline unsigned short f2bf(float f) {
  union { float f; uint32_t u; } c; c.f = f;
  uint32_t r = c.u + 0x7FFFu + ((c.u >> 16) & 1u);
  return (unsigned short)(r >> 16);
}
__device__ inline float bf2f(unsigned short h) {
  union { uint32_t u; float f; } c; c.u = ((uint32_t)h) << 16;
  return c.f;
}

__device__ inline void gld_lds16(const void* g, void* l) {
  __builtin_amdgcn_global_load_lds(
      (const __attribute__((address_space(1))) void*)g,
      (__attribute__((address_space(3))) void*)l, 16, 0, 0);
}

// ---- x1,x2 fp32 -> xb bf16, pair-interleaved [65536, 768]
__global__ void k_convert_x(const float* __restrict__ x1, const float* __restrict__ x2,
                            unsigned short* __restrict__ xb) {
  const int r = blockIdx.x;               // output row
  const int c = threadIdx.x * 4;
  const float* src = ((r & 1) ? x2 : x1) + (size_t)(r >> 1) * D_ + c;
  float4 v = *(const float4*)src;
  union { unsigned short u[4]; uint2 p; } o;
  o.u[0] = f2bf(v.x); o.u[1] = f2bf(v.y); o.u[2] = f2bf(v.z); o.u[3] = f2bf(v.w);
  *(uint2*)(xb + (size_t)r * D_ + c) = o.p;
}

// ---- weight conversions:
//  Wqb/Wkb: straight bf16 copies (row-major [in][out], used as A/Bt of G-gemm)
//  BtMain rows 0..767:  BtMain[n*768+k] = Wv[k][n]   (v columns)
//  BtMlp [384][1536]: n<192 -> W1[k][n]; n>=192 -> W1[(k+768)%1536][n-192]
__global__ void k_convert_w(const float* __restrict__ Wq, const float* __restrict__ Wk,
                            const float* __restrict__ Wv, const float* __restrict__ W1,
                            unsigned short* __restrict__ Wqb, unsigned short* __restrict__ Wkb,
                            unsigned short* __restrict__ BtMain, unsigned short* __restrict__ BtMlp) {
  int idx = blockIdx.x * 256 + threadIdx.x;
  const int S = D_ * D_;
  if (idx < S) { Wqb[idx] = f2bf(Wq[idx]); return; }
  idx -= S;
  if (idx < S) { Wkb[idx] = f2bf(Wk[idx]); return; }
  idx -= S;
  if (idx < S) {
    int n = idx / D_, k = idx - n * D_;
    BtMain[idx] = f2bf(Wv[(size_t)k * D_ + n]);
    return;
  }
  idx -= S;
  if (idx < NMLP * KMLP) {
    int n = idx / KMLP, k = idx - n * KMLP;
    int cc = (n < HID) ? n : n - HID;
    int kk = (n < HID) ? k : ((k < D_) ? k + D_ : k - D_);
    BtMlp[idx] = f2bf(W1[(size_t)kk * HID + cc]);
  }
}

// ---- nk[j] = noise @ Wk ;  gn[a] = Wq[a][:] . nk  (fp32 throughout)
__global__ void k_nk(const float* __restrict__ noise, const float* __restrict__ Wk,
                     float* __restrict__ nk) {
  int j = blockIdx.x * 256 + threadIdx.x;
  if (j >= D_) return;
  float s = 0.f;
  for (int k = 0; k < D_; ++k) s += noise[k] * Wk[(size_t)k * D_ + j];
  nk[j] = s;
}
__global__ void k_gn(const float* __restrict__ Wq, const float* __restrict__ nk,
                     float* __restrict__ gn) {
  int a = blockIdx.x * 256 + threadIdx.x;
  if (a >= D_) return;
  float s = 0.f;
  for (int j = 0; j < D_; ++j) s += Wq[(size_t)a * D_ + j] * nk[j];
  gn[a] = s;
}

// ---- generic 128x128 bf16 GEMM: C = A[M,K] @ Bt[N,K]^T, bf16 out, ldc param.
// LDS XOR-swizzle: chunk(r, q) at index r*4 + (q ^ ((r>>1)&3))  -> 2-way (free) reads.
template<int NTILES, bool SWIZ, int KK>
__launch_bounds__(256)
__global__ void k_gemm(const unsigned short* __restrict__ A,
                       const unsigned short* __restrict__ Bt,
                       unsigned short* __restrict__ C, int ldc) {
  __shared__ __align__(16) short As[128 * 32];
  __shared__ __align__(16) short Bs[128 * 32];
  const int tid = threadIdx.x;
  const int id = blockIdx.x;
  int mi, ni;
  if (SWIZ) {
    // group same-m tiles onto one XCD (assumes round-robin id%8 -> XCD)
    int t = id >> 3;
    mi = (id & 7) * ((gridDim.x / NTILES) >> 3) + t / NTILES;
    ni = t % NTILES;
  } else {
    mi = id / NTILES; ni = id % NTILES;
  }
  const int m0 = mi * 128, n0 = ni * 128;
  const int lane = tid & 63, wave = tid >> 6;
  const int wm = (wave >> 1) * 64, wn = (wave & 1) * 64;
  const int quad = lane >> 4, mr = lane & 15;
  f32x4 acc[4][4];
#pragma unroll
  for (int i = 0; i < 4; ++i)
#pragma unroll
    for (int j = 0; j < 4; ++j) acc[i][j] = (f32x4){0.f, 0.f, 0.f, 0.f};

  // staging: lane tid -> chunk tid; holds (row r, kchunk q) with swizzle
  const int r = tid >> 2;
  const int q = (tid & 3) ^ ((r >> 1) & 3);
  const unsigned short* Ar0 = A + (size_t)(m0 + r) * KK + q * 8;
  const unsigned short* Ar1 = A + (size_t)(m0 + 64 + r) * KK + q * 8;
  const unsigned short* Br0 = Bt + (size_t)(n0 + r) * KK + q * 8;
  const unsigned short* Br1 = Bt + (size_t)(n0 + 64 + r) * KK + q * 8;

  // fragment read offsets (shorts), swizzled; loop-invariant
  int aoff[4], boff[4];
#pragma unroll
  for (int i = 0; i < 4; ++i) {
    int rl = wm + i * 16 + mr;
    aoff[i] = (rl * 4 + (quad ^ ((rl >> 1) & 3))) * 8;
    int nl = wn + i * 16 + mr;
    boff[i] = (nl * 4 + (quad ^ ((nl >> 1) & 3))) * 8;
  }

  for (int k0 = 0; k0 < KK; k0 += 32) {
    __syncthreads();
    gld_lds16(Ar0 + k0, &As[tid * 8]);
    gld_lds16(Ar1 + k0, &As[2048 + tid * 8]);
    gld_lds16(Br0 + k0, &Bs[tid * 8]);
    gld_lds16(Br1 + k0, &Bs[2048 + tid * 8]);
    __syncthreads();
    s16x8 a[4], b[4];
#pragma unroll
    for (int i = 0; i < 4; ++i) a[i] = *(const s16x8*)&As[aoff[i]];
#pragma unroll
    for (int j = 0; j < 4; ++j) b[j] = *(const s16x8*)&Bs[boff[j]];
#pragma unroll
    for (int i = 0; i < 4; ++i)
#pragma unroll
      for (int j = 0; j < 4; ++j)
        acc[i][j] = __builtin_amdgcn_mfma_f32_16x16x32_bf16(a[i], b[j], acc[i][j], 0, 0, 0);
  }
#pragma unroll
  for (int i = 0; i < 4; ++i) {
    int row = m0 + wm + i * 16 + quad * 4;
#pragma unroll
    for (int j = 0; j < 4; ++j) {
      int col = n0 + wn + j * 16 + mr;
#pragma unroll
      for (int t = 0; t < 4; ++t)
        C[(size_t)(row + t) * ldc + col] = f2bf(acc[i][j][t]);
    }
  }
}

// ---- MLP GEMM (both directions fused): A = xb viewed [32768,1536], Bt = BtMlp [384,1536]
// epilogue: gelu(h+b1) . W2 -> atomicAdd into rel[dir][pair]
__launch_bounds__(256)
__global__ void k_gemm_mlp(const unsigned short* __restrict__ A,
                           const unsigned short* __restrict__ Bt,
                           const float* __restrict__ b1, const float* __restrict__ W2,
                           float* __restrict__ rel) {
  __shared__ __align__(16) short As[128 * 32];
  __shared__ __align__(16) short Bs[128 * 32];
  const int tid = threadIdx.x;
  const int id = blockIdx.x;            // 768 blocks
  int t0 = id >> 3;
  const int mi = (id & 7) * 32 + t0 / 3;
  const int ni = t0 % 3;
  const int m0 = mi * 128, n0 = ni * 128;
  const int lane = tid & 63, wave = tid >> 6;
  const int wm = (wave >> 1) * 64, wn = (wave & 1) * 64;
  const int quad = lane >> 4, mr = lane & 15;
  f32x4 acc[4][4];
#pragma unroll
  for (int i = 0; i < 4; ++i)
#pragma unroll
    for (int j = 0; j < 4; ++j) acc[i][j] = (f32x4){0.f, 0.f, 0.f, 0.f};

  const int r = tid >> 2;
  const int q = (tid & 3) ^ ((r >> 1) & 3);
  const unsigned short* Ar0 = A + (size_t)(m0 + r) * KMLP + q * 8;
  const unsigned short* Ar1 = A + (size_t)(m0 + 64 + r) * KMLP + q * 8;
  const unsigned short* Br0 = Bt + (size_t)(n0 + r) * KMLP + q * 8;
  const unsigned short* Br1 = Bt + (size_t)(n0 + 64 + r) * KMLP + q * 8;
  int aoff[4], boff[4];
#pragma unroll
  for (int i = 0; i < 4; ++i) {
    int rl = wm + i * 16 + mr;
    aoff[i] = (rl * 4 + (quad ^ ((rl >> 1) & 3))) * 8;
    int nl = wn + i * 16 + mr;
    boff[i] = (nl * 4 + (quad ^ ((nl >> 1) & 3))) * 8;
  }
  for (int k0 = 0; k0 < KMLP; k0 += 32) {
    __syncthreads();
    gld_lds16(Ar0 + k0, &As[tid * 8]);
    gld_lds16(Ar1 + k0, &As[2048 + tid * 8]);
    gld_lds16(Br0 + k0, &Bs[tid * 8]);
    gld_lds16(Br1 + k0, &Bs[2048 + tid * 8]);
    __syncthreads();
    s16x8 a[4], b[4];
#pragma unroll
    for (int i = 0; i < 4; ++i) a[i] = *(const s16x8*)&As[aoff[i]];
#pragma unroll
    for (int j = 0; j < 4; ++j) b[j] = *(const s16x8*)&Bs[boff[j]];
#pragma unroll
    for (int i = 0; i < 4; ++i)
#pragma unroll
      for (int j = 0; j < 4; ++j)
        acc[i][j] = __builtin_amdgcn_mfma_f32_16x16x32_bf16(a[i], b[j], acc[i][j], 0, 0, 0);
  }
  float part[2][4][4];
#pragma unroll
  for (int d = 0; d < 2; ++d)
#pragma unroll
    for (int i = 0; i < 4; ++i)
#pragma unroll
      for (int t = 0; t < 4; ++t) part[d][i][t] = 0.f;
#pragma unroll
  for (int j = 0; j < 4; ++j) {
    const int colb = n0 + wn + j * 16;        // wave-uniform
    const int dir = (colb >= HID) ? 1 : 0;
    const int cc = colb + mr - dir * HID;     // 0..191
    const float b1v = b1[cc];
    const float w2v = W2[cc];
#pragma unroll
    for (int i = 0; i < 4; ++i)
#pragma unroll
      for (int t = 0; t < 4; ++t) {
        float h = acc[i][j][t] + b1v;
        h = 0.5f * h * (1.f + erff(h * 0.70710678118654752f));
        part[dir][i][t] += h * w2v;
      }
  }
#pragma unroll
  for (int m = 1; m < 16; m <<= 1)
#pragma unroll
    for (int d = 0; d < 2; ++d)
#pragma unroll
      for (int i = 0; i < 4; ++i)
#pragma unroll
        for (int t = 0; t < 4; ++t)
          part[d][i][t] += __shfl_xor(part[d][i][t], m, 64);
  if (mr == 0) {
#pragma unroll
    for (int d = 0; d < 2; ++d)
#pragma unroll
      for (int i = 0; i < 4; ++i) {
        int p = m0 + wm + i * 16 + quad * 4;
#pragma unroll
        for (int t = 0; t < 4; ++t)
          atomicAdd(&rel[(size_t)d * ROWS + p + t], part[d][i][t]);
      }
  }
}

// ---- fusion: one wave per row-pair
__launch_bounds__(256)
__global__ void k_fuse(const float* __restrict__ x1, const float* __restrict__ x2,
                       const unsigned short* __restrict__ vc, const float* __restrict__ gn,
                       const float* __restrict__ rel, const float* __restrict__ b2,
                       float* __restrict__ y) {
  const int p = blockIdx.x * 4 + (threadIdx.x >> 6);
  const int lane = threadIdx.x & 63;
  const unsigned short* L1 = vc + (size_t)(2 * p) * NMAIN;
  const unsigned short* L2 = L1 + NMAIN;
  const float* X1 = x1 + (size_t)p * D_;
  const float* X2 = x2 + (size_t)p * D_;
  float d11 = 0.f, d12 = 0.f, d21 = 0.f, d22 = 0.f;
  for (int c = lane; c < 96; c += 64) {
    const int off = c * 8;
    s16x8 c1 = *(const s16x8*)(L1 + D_ + off);
    s16x8 c2 = *(const s16x8*)(L2 + D_ + off);
    union F8 { float4 v[2]; float f[8]; };
    F8 a1, a2, g;
    a1.v[0] = *(const float4*)(X1 + off); a1.v[1] = *(const float4*)(X1 + off + 4);
    a2.v[0] = *(const float4*)(X2 + off); a2.v[1] = *(const float4*)(X2 + off + 4);
    g.v[0]  = *(const float4*)(gn + off); g.v[1]  = *(const float4*)(gn + off + 4);
#pragma unroll
    for (int e = 0; e < 8; ++e) {
      float fc1 = bf2f(c1[e]), fc2 = bf2f(c2[e]);
      d11 += a1.f[e] * (fc1 + g.f[e]);
      d12 += a1.f[e] * fc2;
      d21 += a2.f[e] * fc1;
      d22 += a2.f[e] * (fc2 + g.f[e]);
    }
  }
#pragma unroll
  for (int m = 1; m < 64; m <<= 1) {
    d11 += __shfl_xor(d11, m, 64);
    d12 += __shfl_xor(d12, m, 64);
    d21 += __shfl_xor(d21, m, 64);
    d22 += __shfl_xor(d22, m, 64);
  }
  const float scale = 0.0360843918243516f;   // 768^-0.5
  const float b2v = b2[0];
  const float r1 = 1.f / (1.f + expf(-(rel[p] + b2v)));
  const float r2 = 1.f / (1.f + expf(-(rel[ROWS + p] + b2v)));
  const float ds1 = d11 * scale, dc1 = r1 * d12 * scale;
  const float ds2 = d22 * scale, dc2 = r2 * d21 * scale;
  const float ws1 = 1.f / (1.f + expf(dc1 - ds1)), wc1 = 1.f - ws1;
  const float ws2 = 1.f / (1.f + expf(dc2 - ds2)), wc2 = 1.f - ws2;
  float* Y1 = y + (size_t)p * D_;
  float* Y2 = y + (size_t)(ROWS + p) * D_;
  for (int c = lane; c < 96; c += 64) {
    const int off = c * 8;
    s16x8 v1 = *(const s16x8*)(L1 + off);
    s16x8 v2 = *(const s16x8*)(L2 + off);
    union F8 { float4 v[2]; float f[8]; };
    F8 a1, a2, o1, o2;
    a1.v[0] = *(const float4*)(X1 + off); a1.v[1] = *(const float4*)(X1 + off + 4);
    a2.v[0] = *(const float4*)(X2 + off); a2.v[1] = *(const float4*)(X2 + off + 4);
#pragma unroll
    for (int e = 0; e < 8; ++e) {
      float fv1 = bf2f(v1[e]), fv2 = bf2f(v2[e]);
      o1.f[e] = a1.f[e] + ws1 * fv1 + wc1 * fv2;
      o2.f[e] = a2.f[e] + ws2 * fv2 + wc2 * fv1;
    }
    *(float4*)(Y1 + off) = o1.v[0]; *(float4*)(Y1 + off + 4) = o1.v[1];
    *(float4*)(Y2 + off) = o2.v[0]; *(float4*)(Y2 + off + 4) = o2.v[1];
  }
}

extern "C" void kernel_launch(void* const* d_in, const int* in_sizes, int n_in,
                              void* d_out, int out_size, void* d_ws, size_t ws_size,
                              hipStream_t stream) {
  const float* x1 = (const float*)d_in[0];
  const float* x2 = (const float*)d_in[1];
  const float* Wq = (const float*)d_in[2];
  const float* Wk = (const float*)d_in[3];
  const float* Wv = (const float*)d_in[4];
  const float* noise = (const float*)d_in[5];
  const float* W1 = (const float*)d_in[6];
  const float* b1 = (const float*)d_in[7];
  const float* W2 = (const float*)d_in[8];
  const float* b2 = (const float*)d_in[9];
  float* y = (float*)d_out;

  char* ws = (char*)d_ws;
  size_t off = 0;
  auto alloc = [&](size_t bytes) {
    char* p = ws + off;
    off += (bytes + 255) & ~(size_t)255;
    return p;
  };
  unsigned short* xb     = (unsigned short*)alloc((size_t)MTOT * D_ * 2);     // 100.7 MB
  unsigned short* vc     = (unsigned short*)alloc((size_t)MTOT * NMAIN * 2);  // 201.3 MB
  unsigned short* BtMain = (unsigned short*)alloc((size_t)NMAIN * D_ * 2);    // v^T | G
  unsigned short* Wqb    = (unsigned short*)alloc((size_t)D_ * D_ * 2);
  unsigned short* Wkb    = (unsigned short*)alloc((size_t)D_ * D_ * 2);
  unsigned short* BtMlp  = (unsigned short*)alloc((size_t)NMLP * KMLP * 2);
  float* nk              = (float*)alloc((size_t)D_ * 4);
  float* gn              = (float*)alloc((size_t)D_ * 4);
  float* rel             = (float*)alloc((size_t)2 * ROWS * 4);

  hipMemsetAsync(rel, 0, (size_t)2 * ROWS * 4, stream);

  k_convert_x<<<dim3(MTOT), 192, 0, stream>>>(x1, x2, xb);

  {
    int total = 3 * D_ * D_ + NMLP * KMLP;
    k_convert_w<<<dim3((total + 255) / 256), 256, 0, stream>>>(Wq, Wk, Wv, W1,
                                                               Wqb, Wkb, BtMain, BtMlp);
  }
  k_nk<<<dim3(3), 256, 0, stream>>>(noise, Wk, nk);
  k_gn<<<dim3(3), 256, 0, stream>>>(Wq, nk, gn);

  // G = Wq @ Wk^T (bf16) -> BtMain rows 768..1535
  k_gemm<6, false, D_><<<dim3(36), 256, 0, stream>>>(Wqb, Wkb, BtMain + (size_t)D_ * D_, D_);

  // main: vc = xb @ [Wv^T; G]^T   (12 n-tiles x 512 m-tiles, XCD-swizzled)
  k_gemm<12, true, D_><<<dim3(6144), 256, 0, stream>>>(xb, BtMain, vc, NMAIN);

  // MLP both dirs: rel logits
  k_gemm_mlp<<<dim3(768), 256, 0, stream>>>(xb, BtMlp, b1, W2, rel);

  // fusion
  k_fuse<<<dim3(ROWS / 4), 256, 0, stream>>>(x1, x2, vc, gn, rel, b2, y);
}